// Round 1
// baseline (242.714 us; speedup 1.0000x reference)
//
#include <hip/hip_runtime.h>

// LightweightConv: x (T,B,C) fp32, weight (H,1,K) fp32 shared across R=C/H channels.
// out[t,b,c] = sum_k w[h(c),k] * x[t-15+k, b, c]   (cross-correlation, pad 15/15)

#define T_DIM 4096
#define B_DIM 8
#define C_DIM 1024
#define H_DIM 16
#define K_DIM 31
#define PAD   15
#define ROWS  (B_DIM * C_DIM)   // 8192 — stride between consecutive t
#define S_LEN 128               // t-strip handled by one thread
#define CH    16                // chunk (outputs per inner block)

__global__ __launch_bounds__(256, 2)
void lconv_kernel(const float* __restrict__ x,
                  const float* __restrict__ w,
                  float* __restrict__ out) {
    __shared__ float lw[H_DIM * K_DIM];   // 496 floats
    const int tid = threadIdx.x;
    for (int i = tid; i < H_DIM * K_DIM; i += 256) lw[i] = w[i];
    __syncthreads();

    const int idx = blockIdx.x * 256 + tid;        // flattened b*C + c, 0..8191
    const int h   = (idx & (C_DIM - 1)) >> 6;      // head = c / 64; wave-uniform (64-aligned)

    // Weights are identical across the wave -> force into SGPRs.
    float wk[K_DIM];
    #pragma unroll
    for (int k = 0; k < K_DIM; ++k) {
        wk[k] = __uint_as_float(
            __builtin_amdgcn_readfirstlane(__float_as_uint(lw[h * K_DIM + k])));
    }

    const int t0 = blockIdx.y * S_LEN;

    float win[K_DIM - 1 + CH];   // 46-entry sliding window: win[m] = x[tb - PAD + m]

    // Prologue: win[0..29] = x[t0-15 .. t0+14]  (uniform bounds check, strip 0 only)
    #pragma unroll
    for (int i = 0; i < K_DIM - 1; ++i) {
        const int t = t0 - PAD + i;
        win[i] = (t >= 0) ? x[(size_t)t * ROWS + idx] : 0.0f;
    }

    for (int cb = 0; cb < S_LEN / CH; ++cb) {
        const int tb = t0 + cb * CH;

        // Load CH new rows: win[30+j] = x[tb+15+j]  (uniform t<T check, last strip only)
        #pragma unroll
        for (int j = 0; j < CH; ++j) {
            const int t = tb + PAD + j;
            win[K_DIM - 1 + j] = (t < T_DIM) ? x[(size_t)t * ROWS + idx] : 0.0f;
        }

        // Compute + store CH outputs (16 independent 31-FMA chains)
        #pragma unroll
        for (int j = 0; j < CH; ++j) {
            float acc = 0.0f;
            #pragma unroll
            for (int k = 0; k < K_DIM; ++k)
                acc = fmaf(wk[k], win[j + k], acc);
            out[(size_t)(tb + j) * ROWS + idx] = acc;
        }

        // Shift window left by CH
        #pragma unroll
        for (int i = 0; i < K_DIM - 1; ++i) win[i] = win[i + CH];
    }
}

extern "C" void kernel_launch(void* const* d_in, const int* in_sizes, int n_in,
                              void* d_out, int out_size, void* d_ws, size_t ws_size,
                              hipStream_t stream) {
    const float* x = (const float*)d_in[0];   // (T, B, C)
    const float* w = (const float*)d_in[1];   // (H, 1, K)
    float* out = (float*)d_out;               // (T, B, C)

    dim3 grid(ROWS / 256, T_DIM / S_LEN);     // (32, 32) = 1024 blocks
    lconv_kernel<<<grid, 256, 0, stream>>>(x, w, out);
}

// Round 2
// 232.522 us; speedup vs baseline: 1.0438x; 1.0438x over previous
//
#include <hip/hip_runtime.h>

// LightweightConv: x (T,B,C) fp32, weight (H,1,K) fp32 shared across R=C/H channels.
// out[t,b,c] = sum_k w[h(c),k] * x[t-15+k, b, c]   (cross-correlation, pad 15/15)

#define T_DIM 4096
#define B_DIM 8
#define C_DIM 1024
#define H_DIM 16
#define K_DIM 31
#define PAD   15
#define ROWS  (B_DIM * C_DIM)   // 8192 — stride between consecutive t
#define CH    16                // outputs per thread (one straight-line chunk)
#define WIN   (K_DIM - 1 + CH)  // 46

__global__ __launch_bounds__(256)
void lconv_kernel(const float* __restrict__ x,
                  const float* __restrict__ w,
                  float* __restrict__ out) {
    __shared__ float lw[H_DIM * K_DIM];   // 496 floats
    const int tid = threadIdx.x;
    for (int i = tid; i < H_DIM * K_DIM; i += 256) lw[i] = w[i];
    __syncthreads();

    const int idx = blockIdx.x * 256 + tid;        // flattened b*C + c, 0..8191
    const int h   = (idx & (C_DIM - 1)) >> 6;      // head = c / 64; wave-uniform (64-aligned)

    // Weights identical across the wave -> force into SGPRs (frees VGPRs).
    float wk[K_DIM];
    #pragma unroll
    for (int k = 0; k < K_DIM; ++k) {
        wk[k] = __uint_as_float(
            __builtin_amdgcn_readfirstlane(__float_as_uint(lw[h * K_DIM + k])));
    }

    const int t0 = blockIdx.y * CH;
    const float* xp = x + (long long)(t0 - PAD) * ROWS + idx;

    float win[WIN];  // straight-line, static indices only -> registers

    if (t0 >= PAD && t0 + CH + PAD <= T_DIM) {
        // Interior fast path: all 46 loads unconditional (wave-uniform branch)
        #pragma unroll
        for (int i = 0; i < WIN; ++i)
            win[i] = xp[(long long)i * ROWS];
    } else {
        #pragma unroll
        for (int i = 0; i < WIN; ++i) {
            const int t = t0 - PAD + i;
            win[i] = (t >= 0 && t < T_DIM) ? xp[(long long)i * ROWS] : 0.0f;
        }
    }

    float* op = out + (long long)t0 * ROWS + idx;
    #pragma unroll
    for (int j = 0; j < CH; ++j) {
        float acc = 0.0f;
        #pragma unroll
        for (int k = 0; k < K_DIM; ++k)
            acc = fmaf(wk[k], win[j + k], acc);
        op[(long long)j * ROWS] = acc;
    }
}

extern "C" void kernel_launch(void* const* d_in, const int* in_sizes, int n_in,
                              void* d_out, int out_size, void* d_ws, size_t ws_size,
                              hipStream_t stream) {
    const float* x = (const float*)d_in[0];   // (T, B, C)
    const float* w = (const float*)d_in[1];   // (H, 1, K)
    float* out = (float*)d_out;               // (T, B, C)

    dim3 grid(ROWS / 256, T_DIM / CH);        // (32, 256) = 8192 blocks
    lconv_kernel<<<grid, 256, 0, stream>>>(x, w, out);
}

// Round 3
// 231.187 us; speedup vs baseline: 1.0499x; 1.0058x over previous
//
#include <hip/hip_runtime.h>

// LightweightConv: x (T,B,C) fp32, weight (H,1,K) fp32 shared across R=C/H channels.
// out[t,b,c] = sum_k w[h(c),k] * x[t-15+k, b, c]   (cross-correlation, pad 15/15)

#define T_DIM 4096
#define B_DIM 8
#define C_DIM 1024
#define H_DIM 16
#define K_DIM 31
#define PAD   15
#define COLS  (B_DIM * C_DIM / 4)   // 2048 float4-columns; stride between t-rows
#define CH    16                    // t-outputs per thread
#define WIN   (K_DIM - 1 + CH)      // 46 float4 window

__global__ __launch_bounds__(256)
void lconv_kernel(const float* __restrict__ x,
                  const float* __restrict__ w,
                  float* __restrict__ out) {
    __shared__ float lw[H_DIM * K_DIM];   // 496 floats
    const int tid = threadIdx.x;
    for (int i = tid; i < H_DIM * K_DIM; i += 256) lw[i] = w[i];
    __syncthreads();

    const int col = blockIdx.x * 256 + tid;     // float4 column, 0..2047 (= b*256 + c/4)
    const int h   = (col & 255) >> 4;           // head = (c % 1024) / 64; uniform per 16 lanes
    const int t0  = blockIdx.y * CH;

    const float4* xp = (const float4*)x + (long long)(t0 - PAD) * COLS + col;

    float4 win[WIN];   // 184 VGPRs — forced fully live by the sched_barrier below

    if (t0 >= PAD && t0 + CH + PAD <= T_DIM) {
        // Interior fast path (wave-uniform branch): 46 unconditional dwordx4 loads
        #pragma unroll
        for (int i = 0; i < WIN; ++i)
            win[i] = xp[(long long)i * COLS];
    } else {
        #pragma unroll
        for (int i = 0; i < WIN; ++i) {
            const int t = t0 - PAD + i;         // uniform predicate -> scalar branch
            win[i] = (t >= 0 && t < T_DIM) ? xp[(long long)i * COLS]
                                           : float4{0.f, 0.f, 0.f, 0.f};
        }
    }

    // Fence: no load may be sunk past this point -> all 46 loads in flight at once.
    __builtin_amdgcn_sched_barrier(0);

    // Weights after the barrier so they aren't live during the load phase.
    float wk[K_DIM];
    #pragma unroll
    for (int k = 0; k < K_DIM; ++k) wk[k] = lw[h * K_DIM + k];

    float4* op = (float4*)out + (long long)t0 * COLS + col;
    #pragma unroll
    for (int j = 0; j < CH; ++j) {
        float4 a = {0.f, 0.f, 0.f, 0.f};
        #pragma unroll
        for (int k = 0; k < K_DIM; ++k) {
            a.x = fmaf(wk[k], win[j + k].x, a.x);
            a.y = fmaf(wk[k], win[j + k].y, a.y);
            a.z = fmaf(wk[k], win[j + k].z, a.z);
            a.w = fmaf(wk[k], win[j + k].w, a.w);
        }
        op[(long long)j * COLS] = a;
    }
}

extern "C" void kernel_launch(void* const* d_in, const int* in_sizes, int n_in,
                              void* d_out, int out_size, void* d_ws, size_t ws_size,
                              hipStream_t stream) {
    const float* x = (const float*)d_in[0];   // (T, B, C)
    const float* w = (const float*)d_in[1];   // (H, 1, K)
    float* out = (float*)d_out;               // (T, B, C)

    dim3 grid(COLS / 256, T_DIM / CH);        // (8, 256) = 2048 blocks, 4 waves each
    lconv_kernel<<<grid, 256, 0, stream>>>(x, w, out);
}